// Round 10
// baseline (715.592 us; speedup 1.0000x reference)
//
#include <hip/hip_runtime.h>
#include <hip/hip_cooperative_groups.h>

namespace cg = cooperative_groups;

// ---------------------------------------------------------------------------
// GCN 2-layer + FC head. f16 MFMA GEMMs, CSR gather, fp32 accumulation.
// Layer 1 aggregate-first:  A_hat(XW) = (A_hat X)W
//   xs   = f16(s.x)                     [N,128]
//   agg1 = xs[i] + sum_{j->i} xs[j]     (gather, 256B rows, x8 unrolled)
//   h1   = f16(relu(s.(agg1@W1) + b1))  (GEMM epilogue fused)   [N,256]
//   t    = f16(s.(h1@W2))               (GEMM epilogue)         [N,128]
//   out  = relu(s.(t[i]+sum t[j]) + b2) @ Wfc + bfc  (fused)    [N,6]
// CSR build + all conversions: ONE cooperative kernel, 5 grid.sync phases.
// Launch chain (5): coop_csr, gather1, gemm1, gemm2, gather_fc.
// ---------------------------------------------------------------------------

typedef _Float16 f16;
typedef __attribute__((ext_vector_type(8))) _Float16 f16x8;
typedef __attribute__((ext_vector_type(4))) float f32x4;

#define GLOAD16(g, l)                                                      \
    __builtin_amdgcn_global_load_lds(                                      \
        (const __attribute__((address_space(1))) void*)(g),                \
        (__attribute__((address_space(3))) void*)(l), 16, 0, 0)

// ---------------- cooperative CSR build + conversions ---------------------
// P0: zero cnt; wt1/wt2 transpose-convert.        sync
// P1: degree count (atomics).                     sync
// P2a: blocks<nblk local excl-scan + disq.        sync
// P2b: block 0 scans nblk partials (nblk<=256).   sync
// P2c: row_ptr/cursor; xs = f16(s.x).             sync
// P3: csr fill via cursor atomics.
__global__ void __launch_bounds__(256)
csr_build_kernel(const int* __restrict__ src, const int* __restrict__ dst,
                 int* __restrict__ cnt, int* __restrict__ slocal,
                 int* __restrict__ partials, int* __restrict__ row_ptr,
                 int* __restrict__ cursor, int* __restrict__ esorted,
                 float* __restrict__ disq,
                 const float* __restrict__ W1, f16* __restrict__ wt1,
                 const float* __restrict__ W2, f16* __restrict__ wt2,
                 const float4* __restrict__ x, f16* __restrict__ xs,
                 int n, int e, int nblk, long long n4) {
    cg::grid_group grid = cg::this_grid();
    const int tid = threadIdx.x;
    const int b = blockIdx.x;
    const int gsz = gridDim.x * 256;
    const int gid = b * 256 + tid;
    __shared__ int lds[256];

    // P0: zero counters + weight transpose-converts
    for (int i = gid; i < n; i += gsz) cnt[i] = 0;
    for (int j = gid; j < 32768; j += gsz) {        // wt1[n][k] = W1[k][n]
        int nn = j >> 7, k = j & 127;
        wt1[j] = (f16)W1[(long long)k * 256 + nn];
    }
    for (int j = gid; j < 32768; j += gsz) {        // wt2[n][k] = W2[k][n]
        int nn = j >> 8, k = j & 255;
        wt2[j] = (f16)W2[(long long)k * 128 + nn];
    }
    grid.sync();

    // P1: degree count
    for (int i = gid; i < e; i += gsz) atomicAdd(&cnt[dst[i]], 1);
    grid.sync();

    // P2a: per-block (1024-elem chunk) local exclusive scan + totals + disq
    if (b < nblk) {
        int base = b * 1024;
        int v[4];
        int sum = 0;
        #pragma unroll
        for (int j = 0; j < 4; j++) {
            int i = base + tid * 4 + j;
            v[j] = (i < n) ? cnt[i] : 0;
            if (i < n) disq[i] = rsqrtf(1.0f + (float)v[j]);
            sum += v[j];
        }
        lds[tid] = sum;
        __syncthreads();
        for (int off = 1; off < 256; off <<= 1) {
            int t = (tid >= off) ? lds[tid - off] : 0;
            __syncthreads();
            lds[tid] += t;
            __syncthreads();
        }
        int excl = lds[tid] - sum;
        if (tid == 255) partials[b] = lds[255];
        int run = excl;
        #pragma unroll
        for (int j = 0; j < 4; j++) {
            int i = base + tid * 4 + j;
            if (i < n) slocal[i] = run;
            run += v[j];
        }
    }
    grid.sync();

    // P2b: block 0 scans the nblk partials (nblk <= 256)
    if (b == 0) {
        int v = (tid < nblk) ? partials[tid] : 0;
        lds[tid] = v;
        __syncthreads();
        for (int off = 1; off < 256; off <<= 1) {
            int t = (tid >= off) ? lds[tid - off] : 0;
            __syncthreads();
            lds[tid] += t;
            __syncthreads();
        }
        if (tid < nblk) partials[tid] = lds[tid] - v;
    }
    grid.sync();

    // P2c: row_ptr / cursor ; xs convert
    if (b < nblk) {
        int base = b * 1024;
        int add = partials[b];
        #pragma unroll
        for (int j = 0; j < 4; j++) {
            int i = base + tid * 4 + j;
            if (i < n) {
                int p = slocal[i] + add;
                row_ptr[i] = p;
                cursor[i] = p;
            }
        }
        if (b == 0 && tid == 0) row_ptr[n] = e;
    }
    for (long long i = gid; i < n4; i += gsz) {
        float4 v = x[i];
        float s = disq[i >> 5];
        union { f16 h[4]; short4 s4; } u;
        u.h[0] = (f16)(v.x * s); u.h[1] = (f16)(v.y * s);
        u.h[2] = (f16)(v.z * s); u.h[3] = (f16)(v.w * s);
        *(short4*)(xs + i * 4) = u.s4;
    }
    grid.sync();

    // P3: CSR fill
    for (int i = gid; i < e; i += gsz) {
        int d = dst[i];
        int pos = atomicAdd(&cursor[d], 1);
        esorted[pos] = src[i];
    }
}

// ---------------- f16 MFMA GEMM: 128x128 tile, BK=64, dbuf gload_lds ------
// C[M][Nc] = f16( epilogue( A[M][K] @ Bt[Nc][K]^T ) )
// MODE 0: *rowscale            MODE 1: relu(*rowscale + bias[col])
// 4 waves (2x2); wave = 64 rows x 64 cols = 4x4 frags of 16x16x32.
// LDS row = 64 f16 = 128B; 16B chunk g at byte (g*16)^((r&7)<<4).
// Staging: LINEAR LDS dest + inverse-swizzled per-lane GLOBAL source (G21).
template <int MODE>
__global__ __launch_bounds__(256)
void gemm_f16_kernel(const f16* __restrict__ A,
                     const f16* __restrict__ Bt,
                     f16* __restrict__ C,
                     const float* __restrict__ rowscale,
                     const float* __restrict__ bias,
                     int M, int K, int Nc) {
    __shared__ __align__(16) char smem[2 * 32 * 1024];   // 2 x (16KB A + 16KB B)
    const int tid = threadIdx.x;
    const int lane = tid & 63;
    const int wid = tid >> 6;
    const int wr = wid >> 1;      // 0..1 -> 64-row half
    const int wc = wid & 1;       // 0..1 -> 64-col half
    const int row0 = blockIdx.y * 128;
    const int col0 = blockIdx.x * 128;
    const bool rows_full = (row0 + 128 <= M);

    f32x4 acc[4][4];
    #pragma unroll
    for (int mr = 0; mr < 4; mr++)
        #pragma unroll
        for (int nr = 0; nr < 4; nr++)
            acc[mr][nr] = (f32x4){0.f, 0.f, 0.f, 0.f};

    auto stage = [&](int buf, int k0) {
        char* as = smem + buf * (32 * 1024);
        char* bs = as + 16 * 1024;
        if (rows_full) {
            #pragma unroll
            for (int i = 0; i < 4; i++) {
                int flat = i * 256 + tid;            // 0..1023 A chunks
                int r = flat >> 3, gp = flat & 7;
                int g = gp ^ (r & 7);                // inverse-swizzled source
                const f16* src = A + (long long)(row0 + r) * K + k0 + g * 8;
                GLOAD16(src, as + (i * 256 + wid * 64) * 16);
            }
        } else {
            #pragma unroll
            for (int i = 0; i < 4; i++) {
                int flat = i * 256 + tid;
                int r = flat >> 3, gp = flat & 7;
                int g = gp ^ (r & 7);
                int gr = row0 + r;
                float4 v = {0.f, 0.f, 0.f, 0.f};
                if (gr < M) v = *(const float4*)(A + (long long)gr * K + k0 + g * 8);
                *(float4*)(as + flat * 16) = v;      // same linear layout
            }
        }
        #pragma unroll
        for (int i = 0; i < 4; i++) {
            int flat = i * 256 + tid;                // 0..1023 B chunks
            int nn = flat >> 3, gp = flat & 7;
            int g = gp ^ (nn & 7);
            const f16* src = Bt + (long long)(col0 + nn) * K + k0 + g * 8;
            GLOAD16(src, bs + (i * 256 + wid * 64) * 16);
        }
    };

    auto compute = [&](int buf) {
        char* as = smem + buf * (32 * 1024);
        char* bs = as + 16 * 1024;
        #pragma unroll
        for (int ks = 0; ks < 2; ks++) {
            const int kb = (ks * 32 + ((lane >> 4) * 8)) * 2;
            f16x8 af[4], bf[4];
            #pragma unroll
            for (int mr = 0; mr < 4; mr++) {
                int r = wr * 64 + mr * 16 + (lane & 15);
                af[mr] = *(const f16x8*)(as + r * 128 + (kb ^ ((r & 7) << 4)));
            }
            #pragma unroll
            for (int nr = 0; nr < 4; nr++) {
                int c = wc * 64 + nr * 16 + (lane & 15);
                bf[nr] = *(const f16x8*)(bs + c * 128 + (kb ^ ((c & 7) << 4)));
            }
            #pragma unroll
            for (int mr = 0; mr < 4; mr++)
                #pragma unroll
                for (int nr = 0; nr < 4; nr++)
                    acc[mr][nr] = __builtin_amdgcn_mfma_f32_16x16x32_f16(
                        af[mr], bf[nr], acc[mr][nr], 0, 0, 0);
        }
    };

    const int nt = K >> 6;
    stage(0, 0);
    __syncthreads();
    int cur = 0;
    for (int t = 0; t < nt; t++) {
        if (t + 1 < nt) stage(cur ^ 1, (t + 1) * 64);
        compute(cur);
        __syncthreads();
        cur ^= 1;
    }

    // epilogue: C/D map col=lane&15, row=(lane>>4)*4+reg  [m89-verified]
    float bv[4] = {0.f, 0.f, 0.f, 0.f};
    if (MODE == 1) {
        #pragma unroll
        for (int nr = 0; nr < 4; nr++)
            bv[nr] = bias[col0 + wc * 64 + nr * 16 + (lane & 15)];
    }
    #pragma unroll
    for (int mr = 0; mr < 4; mr++) {
        #pragma unroll
        for (int reg = 0; reg < 4; reg++) {
            int row = row0 + wr * 64 + mr * 16 + (lane >> 4) * 4 + reg;
            if (row < M) {
                float s = rowscale[row];
                int col = col0 + wc * 64 + (lane & 15);
                #pragma unroll
                for (int nr = 0; nr < 4; nr++) {
                    float v = acc[mr][nr][reg] * s;
                    if (MODE == 1) v = fmaxf(v + bv[nr], 0.0f);
                    C[(long long)row * Nc + col + nr * 16] = (f16)v;
                }
            }
        }
    }
}

// ---------------- gather (pure sum, 128-ch f16 rows, x8 unrolled) --------
__global__ void gather_sum_f16_kernel(const float4* __restrict__ h,
                                      float4* __restrict__ out,
                                      const int* __restrict__ row_ptr,
                                      const int* __restrict__ esorted, int n) {
    int lane = threadIdx.x & 63;
    long long wave = (blockIdx.x * (long long)blockDim.x + threadIdx.x) >> 6;
    int sub = lane >> 4;            // 4 nodes/wave
    int sl = lane & 15;
    long long node = wave * 4 + sub;
    if (node >= n) return;
    int beg = row_ptr[node], end = row_ptr[node + 1];
    float acc[8];
    {
        float4 v = h[node * 16 + sl];
        const f16* hp = (const f16*)&v;
        #pragma unroll
        for (int j = 0; j < 8; j++) acc[j] = (float)hp[j];
    }
    int e = beg;
    for (; e + 8 <= end; e += 8) {  // 8 independent row loads in flight
        int s[8];
        #pragma unroll
        for (int u = 0; u < 8; u++) s[u] = esorted[e + u];
        float4 v[8];
        #pragma unroll
        for (int u = 0; u < 8; u++) v[u] = h[(long long)s[u] * 16 + sl];
        #pragma unroll
        for (int u = 0; u < 8; u++) {
            const f16* p = (const f16*)&v[u];
            #pragma unroll
            for (int j = 0; j < 8; j++) acc[j] += (float)p[j];
        }
    }
    for (; e < end; e++) {
        int s = esorted[e];
        float4 v = h[(long long)s * 16 + sl];
        const f16* hp = (const f16*)&v;
        #pragma unroll
        for (int j = 0; j < 8; j++) acc[j] += (float)hp[j];
    }
    union { float4 f4; f16 hh[8]; } o;
    #pragma unroll
    for (int j = 0; j < 8; j++) o.hh[j] = (f16)acc[j];
    out[node * 16 + sl] = o.f4;
}

// ---------------- gather2 + relu + FC head (x8 unrolled) -----------------
// h2 = relu(disq[node]*(t[node]+sum t[src]) + b2);  out = h2 @ Wfc + bfc
__global__ void gather_fc_kernel(const float4* __restrict__ t,
                                 const int* __restrict__ row_ptr,
                                 const int* __restrict__ esorted,
                                 const float* __restrict__ disq,
                                 const float* __restrict__ b2,
                                 const float* __restrict__ Wfc,   // [128][6]
                                 const float* __restrict__ bfc,   // [6]
                                 float* __restrict__ out, int n) {
    __shared__ float wf[6 * 132];    // transposed [6][128], padded row 132
    for (int i = threadIdx.x; i < 6 * 128; i += 256) {
        int k = i >> 7, ch = i & 127;
        wf[k * 132 + ch] = Wfc[ch * 6 + k];
    }
    __syncthreads();
    int lane = threadIdx.x & 63;
    long long wave = (blockIdx.x * (long long)blockDim.x + threadIdx.x) >> 6;
    int sub = lane >> 4;
    int sl = lane & 15;
    long long node = wave * 4 + sub;
    if (node >= n) return;
    int beg = row_ptr[node], end = row_ptr[node + 1];
    float acc[8];
    {
        float4 v = t[node * 16 + sl];
        const f16* hp = (const f16*)&v;
        #pragma unroll
        for (int j = 0; j < 8; j++) acc[j] = (float)hp[j];
    }
    int e = beg;
    for (; e + 8 <= end; e += 8) {
        int s[8];
        #pragma unroll
        for (int u = 0; u < 8; u++) s[u] = esorted[e + u];
        float4 v[8];
        #pragma unroll
        for (int u = 0; u < 8; u++) v[u] = t[(long long)s[u] * 16 + sl];
        #pragma unroll
        for (int u = 0; u < 8; u++) {
            const f16* p = (const f16*)&v[u];
            #pragma unroll
            for (int j = 0; j < 8; j++) acc[j] += (float)p[j];
        }
    }
    for (; e < end; e++) {
        int s = esorted[e];
        float4 v = t[(long long)s * 16 + sl];
        const f16* hp = (const f16*)&v;
        #pragma unroll
        for (int j = 0; j < 8; j++) acc[j] += (float)hp[j];
    }
    float sc = disq[node];
    const float4* b4 = (const float4*)(b2 + sl * 8);
    float4 bb0 = b4[0], bb1 = b4[1];
    float bb[8] = {bb0.x, bb0.y, bb0.z, bb0.w, bb1.x, bb1.y, bb1.z, bb1.w};
    float h2[8];
    #pragma unroll
    for (int j = 0; j < 8; j++)
        h2[j] = fmaxf(fmaf(acc[j], sc, bb[j]), 0.0f);
    float p[6];
    #pragma unroll
    for (int k = 0; k < 6; k++) {
        float s = 0.f;
        #pragma unroll
        for (int j = 0; j < 8; j++) s += h2[j] * wf[k * 132 + sl * 8 + j];
        p[k] = s;
    }
    #pragma unroll
    for (int off = 8; off >= 1; off >>= 1)
        #pragma unroll
        for (int k = 0; k < 6; k++) p[k] += __shfl_down(p[k], off);
    if (sl == 0) {
        #pragma unroll
        for (int k = 0; k < 6; k++)
            out[(long long)node * 6 + k] = p[k] + bfc[k];
    }
}

extern "C" void kernel_launch(void* const* d_in, const int* in_sizes, int n_in,
                              void* d_out, int out_size, void* d_ws, size_t ws_size,
                              hipStream_t stream) {
    const float* x   = (const float*)d_in[0];
    const float* W1  = (const float*)d_in[1];
    const float* b1  = (const float*)d_in[2];
    const float* W2  = (const float*)d_in[3];
    const float* b2  = (const float*)d_in[4];
    const float* Wfc = (const float*)d_in[5];
    const float* bfc = (const float*)d_in[6];
    const int* edges = (const int*)d_in[7];

    const int N = in_sizes[0] / 128;       // 50000
    const int E = in_sizes[7] / 2;         // 500000
    const int* e_src = edges;
    const int* e_dst = edges + E;

    char* ws = (char*)d_ws;
    size_t off = 0;
    auto alloc = [&](size_t bytes) {
        void* p = ws + off;
        off += (bytes + 255) & ~(size_t)255;
        return p;
    };
    const int NB = (N + 1023) / 1024;                    // 49 (<=256 required)
    float* disq     = (float*)alloc((size_t)N * 4);
    int*   cnt      = (int*)  alloc((size_t)N * 4);
    int*   slocal   = (int*)  alloc((size_t)N * 4);
    int*   partials = (int*)  alloc((size_t)NB * 4);
    int*   row_ptr  = (int*)  alloc((size_t)(N + 1) * 4);
    int*   cursor   = (int*)  alloc((size_t)N * 4);
    int*   esorted  = (int*)  alloc((size_t)E * 4);
    f16*   xs       = (f16*)  alloc((size_t)N * 128 * 2);
    f16*   wt1      = (f16*)  alloc((size_t)256 * 128 * 2);  // [256][128]
    f16*   wt2      = (f16*)  alloc((size_t)128 * 256 * 2);  // [128][256]
    f16*   agg1     = (f16*)  alloc((size_t)N * 128 * 2);
    f16*   h1       = (f16*)  alloc((size_t)N * 256 * 2);
    f16*   tbuf     = (f16*)  alloc((size_t)N * 128 * 2);
    (void)ws_size; (void)n_in;

    float* out = (float*)d_out; (void)out_size;

    // --- cooperative CSR build + conversions (1 launch, 5 grid syncs) ---
    {
        long long n4 = (long long)N * 128 / 4;
        int nblk = NB;
        void* args[] = {
            (void*)&e_src, (void*)&e_dst, (void*)&cnt, (void*)&slocal,
            (void*)&partials, (void*)&row_ptr, (void*)&cursor, (void*)&esorted,
            (void*)&disq, (void*)&W1, (void*)&wt1, (void*)&W2, (void*)&wt2,
            (void*)&x, (void*)&xs, (void*)&N, (void*)&E, (void*)&nblk,
            (void*)&n4
        };
        hipLaunchCooperativeKernel((const void*)csr_build_kernel,
                                   dim3(1024), dim3(256), args, 0, stream);
    }

    // --- layer 1: gather xs -> agg1 ; GEMM (+scale+bias+relu) -> h1 ---
    {
        long long waves = ((long long)N + 3) / 4;
        int blocks = (int)((waves + 3) / 4);
        gather_sum_f16_kernel<<<blocks, 256, 0, stream>>>(
            (const float4*)xs, (float4*)agg1, row_ptr, esorted, N);
    }
    {
        dim3 g(256 / 128, (N + 127) / 128);
        gemm_f16_kernel<1><<<g, 256, 0, stream>>>(agg1, wt1, h1, disq, b1,
                                                  N, 128, 256);
    }

    // --- layer 2: GEMM (+scale) -> tbuf ; gather + relu + FC -> out ---
    {
        dim3 g(128 / 128, (N + 127) / 128);
        gemm_f16_kernel<0><<<g, 256, 0, stream>>>(h1, wt2, tbuf, disq, nullptr,
                                                  N, 256, 128);
    }
    {
        long long waves = ((long long)N + 3) / 4;
        int blocks = (int)((waves + 3) / 4);
        gather_fc_kernel<<<blocks, 256, 0, stream>>>(
            (const float4*)tbuf, row_ptr, esorted, disq, b2, Wfc, bfc, out, N);
    }
}

// Round 11
// 228.413 us; speedup vs baseline: 3.1329x; 3.1329x over previous
//
#include <hip/hip_runtime.h>

// ---------------------------------------------------------------------------
// GCN 2-layer + FC head. f16 MFMA GEMMs, CSR gather, fp32 accumulation.
// Layer 1 aggregate-first:  A_hat(XW) = (A_hat X)W
//   xs   = f16(s.x)                     [N,128]
//   agg1 = xs[i] + sum_{j->i} xs[j]     (gather, 256B rows, x8 unrolled)
//   h1   = f16(relu(s.(agg1@W1) + b1))  (GEMM epilogue fused)   [N,256]
//   t    = f16(s.(h1@W2))               (GEMM epilogue)         [N,128]
//   out  = relu(s.(t[i]+sum t[j]) + b2) @ Wfc + bfc  (fused)    [N,6]
// GEMM: 128x128 tile, global_load_lds staging (source-swizzled), dbuf.
// NOTE (R10 lesson): hipLaunchCooperativeKernel grid.sync() ~100us each on
// MI355X (cross-XCD barrier) -- kernel boundaries are CHEAPER. Multi-kernel.
// Launch chain (9): memset, count+wtcvt, scan1, scan3+xscvt(self-prefix),
//                   csr_fill, gather1, gemm1, gemm2, gather_fc.
// ---------------------------------------------------------------------------

typedef _Float16 f16;
typedef __attribute__((ext_vector_type(8))) _Float16 f16x8;
typedef __attribute__((ext_vector_type(4))) float f32x4;

#define GLOAD16(g, l)                                                      \
    __builtin_amdgcn_global_load_lds(                                      \
        (const __attribute__((address_space(1))) void*)(g),                \
        (__attribute__((address_space(3))) void*)(l), 16, 0, 0)

// ---------------- fused: degree count + weight transpose-convert ----------
__global__ void count_wt_kernel(const int* __restrict__ dst, int* __restrict__ cnt,
                                int e,
                                const float* __restrict__ W1, f16* __restrict__ wt1,
                                const float* __restrict__ W2, f16* __restrict__ wt2) {
    int b = blockIdx.x;
    if (b < 128) {
        int j = b * 256 + threadIdx.x;
        int nn = j >> 7, k = j & 127;
        wt1[j] = (f16)W1[(long long)k * 256 + nn];
    } else if (b < 256) {
        int j = (b - 128) * 256 + threadIdx.x;
        int nn = j >> 8, k = j & 255;
        wt2[j] = (f16)W2[(long long)k * 128 + nn];
    } else {
        for (int i = (b - 256) * 256 + (int)threadIdx.x; i < e; i += 2048 * 256)
            atomicAdd(&cnt[dst[i]], 1);
    }
}

// Phase 1: per-block (256 thr x 4) local exclusive scan + RAW totals + disq.
__global__ void scan1_kernel(const int* __restrict__ cnt, int* __restrict__ local,
                             int* __restrict__ partials, float* __restrict__ disq,
                             int n) {
    __shared__ int lds[256];
    int base = blockIdx.x * 1024;
    int t = threadIdx.x;
    int v[4];
    int sum = 0;
    #pragma unroll
    for (int j = 0; j < 4; j++) {
        int i = base + t * 4 + j;
        v[j] = (i < n) ? cnt[i] : 0;
        if (i < n) disq[i] = rsqrtf(1.0f + (float)v[j]);
        sum += v[j];
    }
    lds[t] = sum;
    __syncthreads();
    for (int off = 1; off < 256; off <<= 1) {
        int x = (t >= off) ? lds[t - off] : 0;
        __syncthreads();
        lds[t] += x;
        __syncthreads();
    }
    int excl = lds[t] - sum;
    if (t == 255) partials[blockIdx.x] = lds[255];   // raw block total
    int run = excl;
    #pragma unroll
    for (int j = 0; j < 4; j++) {
        int i = base + t * 4 + j;
        if (i < n) local[i] = run;
        run += v[j];
    }
}

// Phase 2 (+xs convert): blocks [0,nb): self-compute prefix of raw partials
// (nb<=256, L2-cached broadcast reads) then row_ptr/cursor; blocks [nb,..): xs.
__global__ void scan3_xs_kernel(const int* __restrict__ local,
                                const int* __restrict__ partials,
                                int* __restrict__ row_ptr, int* __restrict__ cursor,
                                int n, int e_total, int nb,
                                const float4* __restrict__ x,
                                const float* __restrict__ disq,
                                f16* __restrict__ xs, long long n4) {
    int b = blockIdx.x;
    int t = threadIdx.x;
    if (b < nb) {
        int add = 0;
        for (int i = 0; i < b; i++) add += partials[i];  // uniform, ~49 iters
        int base = b * 1024;
        #pragma unroll
        for (int j = 0; j < 4; j++) {
            int i = base + t * 4 + j;
            if (i < n) {
                int p = local[i] + add;
                row_ptr[i] = p;
                cursor[i] = p;
            }
        }
        if (b == 0 && t == 0) row_ptr[n] = e_total;
        return;
    }
    long long i = (long long)(b - nb) * 256 + t;
    if (i < n4) {
        float4 v = x[i];
        float s = disq[i >> 5];
        union { f16 h[4]; short4 s4; } u;
        u.h[0] = (f16)(v.x * s); u.h[1] = (f16)(v.y * s);
        u.h[2] = (f16)(v.z * s); u.h[3] = (f16)(v.w * s);
        *(short4*)(xs + i * 4) = u.s4;
    }
}

__global__ void csr_fill_kernel(const int* __restrict__ src, const int* __restrict__ dst,
                                int* __restrict__ cursor, int* __restrict__ esorted,
                                int e) {
    for (int i = blockIdx.x * blockDim.x + threadIdx.x; i < e;
         i += gridDim.x * blockDim.x) {
        int d = dst[i];
        int pos = atomicAdd(&cursor[d], 1);
        esorted[pos] = src[i];
    }
}

// ---------------- f16 MFMA GEMM: 128x128 tile, BK=64, dbuf gload_lds ------
// C[M][Nc] = f16( epilogue( A[M][K] @ Bt[Nc][K]^T ) )
// MODE 0: *rowscale            MODE 1: relu(*rowscale + bias[col])
// 4 waves (2x2); wave = 64 rows x 64 cols = 4x4 frags of 16x16x32.
// LDS row = 64 f16 = 128B; 16B chunk g at byte (g*16)^((r&7)<<4).
// Staging: LINEAR LDS dest + inverse-swizzled per-lane GLOBAL source (G21).
template <int MODE>
__global__ __launch_bounds__(256)
void gemm_f16_kernel(const f16* __restrict__ A,
                     const f16* __restrict__ Bt,
                     f16* __restrict__ C,
                     const float* __restrict__ rowscale,
                     const float* __restrict__ bias,
                     int M, int K, int Nc) {
    __shared__ __align__(16) char smem[2 * 32 * 1024];   // 2 x (16KB A + 16KB B)
    const int tid = threadIdx.x;
    const int lane = tid & 63;
    const int wid = tid >> 6;
    const int wr = wid >> 1;      // 0..1 -> 64-row half
    const int wc = wid & 1;       // 0..1 -> 64-col half
    const int row0 = blockIdx.y * 128;
    const int col0 = blockIdx.x * 128;
    const bool rows_full = (row0 + 128 <= M);

    f32x4 acc[4][4];
    #pragma unroll
    for (int mr = 0; mr < 4; mr++)
        #pragma unroll
        for (int nr = 0; nr < 4; nr++)
            acc[mr][nr] = (f32x4){0.f, 0.f, 0.f, 0.f};

    auto stage = [&](int buf, int k0) {
        char* as = smem + buf * (32 * 1024);
        char* bs = as + 16 * 1024;
        if (rows_full) {
            #pragma unroll
            for (int i = 0; i < 4; i++) {
                int flat = i * 256 + tid;            // 0..1023 A chunks
                int r = flat >> 3, gp = flat & 7;
                int g = gp ^ (r & 7);                // inverse-swizzled source
                const f16* src = A + (long long)(row0 + r) * K + k0 + g * 8;
                GLOAD16(src, as + (i * 256 + wid * 64) * 16);
            }
        } else {
            #pragma unroll
            for (int i = 0; i < 4; i++) {
                int flat = i * 256 + tid;
                int r = flat >> 3, gp = flat & 7;
                int g = gp ^ (r & 7);
                int gr = row0 + r;
                float4 v = {0.f, 0.f, 0.f, 0.f};
                if (gr < M) v = *(const float4*)(A + (long long)gr * K + k0 + g * 8);
                *(float4*)(as + flat * 16) = v;      // same linear layout
            }
        }
        #pragma unroll
        for (int i = 0; i < 4; i++) {
            int flat = i * 256 + tid;                // 0..1023 B chunks
            int nn = flat >> 3, gp = flat & 7;
            int g = gp ^ (nn & 7);
            const f16* src = Bt + (long long)(col0 + nn) * K + k0 + g * 8;
            GLOAD16(src, bs + (i * 256 + wid * 64) * 16);
        }
    };

    auto compute = [&](int buf) {
        char* as = smem + buf * (32 * 1024);
        char* bs = as + 16 * 1024;
        #pragma unroll
        for (int ks = 0; ks < 2; ks++) {
            const int kb = (ks * 32 + ((lane >> 4) * 8)) * 2;
            f16x8 af[4], bf[4];
            #pragma unroll
            for (int mr = 0; mr < 4; mr++) {
                int r = wr * 64 + mr * 16 + (lane & 15);
                af[mr] = *(const f16x8*)(as + r * 128 + (kb ^ ((r & 7) << 4)));
            }
            #pragma unroll
            for (int nr = 0; nr < 4; nr++) {
                int c = wc * 64 + nr * 16 + (lane & 15);
                bf[nr] = *(const f16x8*)(bs + c * 128 + (kb ^ ((c & 7) << 4)));
            }
            #pragma unroll
            for (int mr = 0; mr < 4; mr++)
                #pragma unroll
                for (int nr = 0; nr < 4; nr++)
                    acc[mr][nr] = __builtin_amdgcn_mfma_f32_16x16x32_f16(
                        af[mr], bf[nr], acc[mr][nr], 0, 0, 0);
        }
    };

    const int nt = K >> 6;
    stage(0, 0);
    __syncthreads();
    int cur = 0;
    for (int t = 0; t < nt; t++) {
        if (t + 1 < nt) stage(cur ^ 1, (t + 1) * 64);
        compute(cur);
        __syncthreads();
        cur ^= 1;
    }

    // epilogue: C/D map col=lane&15, row=(lane>>4)*4+reg  [m89-verified]
    float bv[4] = {0.f, 0.f, 0.f, 0.f};
    if (MODE == 1) {
        #pragma unroll
        for (int nr = 0; nr < 4; nr++)
            bv[nr] = bias[col0 + wc * 64 + nr * 16 + (lane & 15)];
    }
    #pragma unroll
    for (int mr = 0; mr < 4; mr++) {
        #pragma unroll
        for (int reg = 0; reg < 4; reg++) {
            int row = row0 + wr * 64 + mr * 16 + (lane >> 4) * 4 + reg;
            if (row < M) {
                float s = rowscale[row];
                int col = col0 + wc * 64 + (lane & 15);
                #pragma unroll
                for (int nr = 0; nr < 4; nr++) {
                    float v = acc[mr][nr][reg] * s;
                    if (MODE == 1) v = fmaxf(v + bv[nr], 0.0f);
                    C[(long long)row * Nc + col + nr * 16] = (f16)v;
                }
            }
        }
    }
}

// ---------------- gather (pure sum, 128-ch f16 rows, x8 unrolled) --------
__global__ void gather_sum_f16_kernel(const float4* __restrict__ h,
                                      float4* __restrict__ out,
                                      const int* __restrict__ row_ptr,
                                      const int* __restrict__ esorted, int n) {
    int lane = threadIdx.x & 63;
    long long wave = (blockIdx.x * (long long)blockDim.x + threadIdx.x) >> 6;
    int sub = lane >> 4;            // 4 nodes/wave
    int sl = lane & 15;
    long long node = wave * 4 + sub;
    if (node >= n) return;
    int beg = row_ptr[node], end = row_ptr[node + 1];
    float acc[8];
    {
        float4 v = h[node * 16 + sl];
        const f16* hp = (const f16*)&v;
        #pragma unroll
        for (int j = 0; j < 8; j++) acc[j] = (float)hp[j];
    }
    int e = beg;
    for (; e + 8 <= end; e += 8) {  // 8 independent row loads in flight
        int s[8];
        #pragma unroll
        for (int u = 0; u < 8; u++) s[u] = esorted[e + u];
        float4 v[8];
        #pragma unroll
        for (int u = 0; u < 8; u++) v[u] = h[(long long)s[u] * 16 + sl];
        #pragma unroll
        for (int u = 0; u < 8; u++) {
            const f16* p = (const f16*)&v[u];
            #pragma unroll
            for (int j = 0; j < 8; j++) acc[j] += (float)p[j];
        }
    }
    for (; e < end; e++) {
        int s = esorted[e];
        float4 v = h[(long long)s * 16 + sl];
        const f16* hp = (const f16*)&v;
        #pragma unroll
        for (int j = 0; j < 8; j++) acc[j] += (float)hp[j];
    }
    union { float4 f4; f16 hh[8]; } o;
    #pragma unroll
    for (int j = 0; j < 8; j++) o.hh[j] = (f16)acc[j];
    out[node * 16 + sl] = o.f4;
}

// ---------------- gather2 + relu + FC head (x8 unrolled) -----------------
// h2 = relu(disq[node]*(t[node]+sum t[src]) + b2);  out = h2 @ Wfc + bfc
__global__ void gather_fc_kernel(const float4* __restrict__ t,
                                 const int* __restrict__ row_ptr,
                                 const int* __restrict__ esorted,
                                 const float* __restrict__ disq,
                                 const float* __restrict__ b2,
                                 const float* __restrict__ Wfc,   // [128][6]
                                 const float* __restrict__ bfc,   // [6]
                                 float* __restrict__ out, int n) {
    __shared__ float wf[6 * 132];    // transposed [6][128], padded row 132
    for (int i = threadIdx.x; i < 6 * 128; i += 256) {
        int k = i >> 7, ch = i & 127;
        wf[k * 132 + ch] = Wfc[ch * 6 + k];
    }
    __syncthreads();
    int lane = threadIdx.x & 63;
    long long wave = (blockIdx.x * (long long)blockDim.x + threadIdx.x) >> 6;
    int sub = lane >> 4;
    int sl = lane & 15;
    long long node = wave * 4 + sub;
    if (node >= n) return;
    int beg = row_ptr[node], end = row_ptr[node + 1];
    float acc[8];
    {
        float4 v = t[node * 16 + sl];
        const f16* hp = (const f16*)&v;
        #pragma unroll
        for (int j = 0; j < 8; j++) acc[j] = (float)hp[j];
    }
    int e = beg;
    for (; e + 8 <= end; e += 8) {
        int s[8];
        #pragma unroll
        for (int u = 0; u < 8; u++) s[u] = esorted[e + u];
        float4 v[8];
        #pragma unroll
        for (int u = 0; u < 8; u++) v[u] = t[(long long)s[u] * 16 + sl];
        #pragma unroll
        for (int u = 0; u < 8; u++) {
            const f16* p = (const f16*)&v[u];
            #pragma unroll
            for (int j = 0; j < 8; j++) acc[j] += (float)p[j];
        }
    }
    for (; e < end; e++) {
        int s = esorted[e];
        float4 v = t[(long long)s * 16 + sl];
        const f16* hp = (const f16*)&v;
        #pragma unroll
        for (int j = 0; j < 8; j++) acc[j] += (float)hp[j];
    }
    float sc = disq[node];
    const float4* b4 = (const float4*)(b2 + sl * 8);
    float4 bb0 = b4[0], bb1 = b4[1];
    float bb[8] = {bb0.x, bb0.y, bb0.z, bb0.w, bb1.x, bb1.y, bb1.z, bb1.w};
    float h2[8];
    #pragma unroll
    for (int j = 0; j < 8; j++)
        h2[j] = fmaxf(fmaf(acc[j], sc, bb[j]), 0.0f);
    float p[6];
    #pragma unroll
    for (int k = 0; k < 6; k++) {
        float s = 0.f;
        #pragma unroll
        for (int j = 0; j < 8; j++) s += h2[j] * wf[k * 132 + sl * 8 + j];
        p[k] = s;
    }
    #pragma unroll
    for (int off = 8; off >= 1; off >>= 1)
        #pragma unroll
        for (int k = 0; k < 6; k++) p[k] += __shfl_down(p[k], off);
    if (sl == 0) {
        #pragma unroll
        for (int k = 0; k < 6; k++)
            out[(long long)node * 6 + k] = p[k] + bfc[k];
    }
}

extern "C" void kernel_launch(void* const* d_in, const int* in_sizes, int n_in,
                              void* d_out, int out_size, void* d_ws, size_t ws_size,
                              hipStream_t stream) {
    const float* x   = (const float*)d_in[0];
    const float* W1  = (const float*)d_in[1];
    const float* b1  = (const float*)d_in[2];
    const float* W2  = (const float*)d_in[3];
    const float* b2  = (const float*)d_in[4];
    const float* Wfc = (const float*)d_in[5];
    const float* bfc = (const float*)d_in[6];
    const int* edges = (const int*)d_in[7];

    const int N = in_sizes[0] / 128;       // 50000
    const int E = in_sizes[7] / 2;         // 500000
    const int* e_src = edges;
    const int* e_dst = edges + E;

    char* ws = (char*)d_ws;
    size_t off = 0;
    auto alloc = [&](size_t bytes) {
        void* p = ws + off;
        off += (bytes + 255) & ~(size_t)255;
        return p;
    };
    const int NB = (N + 1023) / 1024;                    // 49 (<=256 required)
    float* disq     = (float*)alloc((size_t)N * 4);
    int*   cnt      = (int*)  alloc((size_t)N * 4);
    int*   slocal   = (int*)  alloc((size_t)N * 4);
    int*   partials = (int*)  alloc((size_t)NB * 4);
    int*   row_ptr  = (int*)  alloc((size_t)(N + 1) * 4);
    int*   cursor   = (int*)  alloc((size_t)N * 4);
    int*   esorted  = (int*)  alloc((size_t)E * 4);
    f16*   xs       = (f16*)  alloc((size_t)N * 128 * 2);
    f16*   wt1      = (f16*)  alloc((size_t)256 * 128 * 2);  // [256][128]
    f16*   wt2      = (f16*)  alloc((size_t)128 * 256 * 2);  // [128][256]
    f16*   agg1     = (f16*)  alloc((size_t)N * 128 * 2);
    f16*   h1       = (f16*)  alloc((size_t)N * 256 * 2);
    f16*   tbuf     = (f16*)  alloc((size_t)N * 128 * 2);
    (void)ws_size; (void)n_in;

    float* out = (float*)d_out; (void)out_size;

    // --- CSR + degree scales + conversions ---
    hipMemsetAsync(cnt, 0, (size_t)N * sizeof(int), stream);
    count_wt_kernel<<<256 + 2048, 256, 0, stream>>>(e_dst, cnt, E,
                                                    W1, wt1, W2, wt2);
    scan1_kernel<<<NB, 256, 0, stream>>>(cnt, slocal, partials, disq, N);
    {
        long long n4 = (long long)N * 128 / 4;
        int xb = (int)((n4 + 255) / 256);
        scan3_xs_kernel<<<NB + xb, 256, 0, stream>>>(
            slocal, partials, row_ptr, cursor, N, E, NB,
            (const float4*)x, disq, xs, n4);
    }
    csr_fill_kernel<<<2048, 256, 0, stream>>>(e_src, e_dst, cursor, esorted, E);

    // --- layer 1: gather xs -> agg1 ; GEMM (+scale+bias+relu) -> h1 ---
    {
        long long waves = ((long long)N + 3) / 4;
        int blocks = (int)((waves + 3) / 4);
        gather_sum_f16_kernel<<<blocks, 256, 0, stream>>>(
            (const float4*)xs, (float4*)agg1, row_ptr, esorted, N);
    }
    {
        dim3 g(256 / 128, (N + 127) / 128);
        gemm_f16_kernel<1><<<g, 256, 0, stream>>>(agg1, wt1, h1, disq, b1,
                                                  N, 128, 256);
    }

    // --- layer 2: GEMM (+scale) -> tbuf ; gather + relu + FC -> out ---
    {
        dim3 g(128 / 128, (N + 127) / 128);
        gemm_f16_kernel<0><<<g, 256, 0, stream>>>(h1, wt2, tbuf, disq, nullptr,
                                                  N, 256, 128);
    }
    {
        long long waves = ((long long)N + 3) / 4;
        int blocks = (int)((waves + 3) / 4);
        gather_fc_kernel<<<blocks, 256, 0, stream>>>(
            (const float4*)tbuf, row_ptr, esorted, disq, b2, Wfc, bfc, out, N);
    }
}